// Round 4
// baseline (9766.264 us; speedup 1.0000x reference)
//
#include <hip/hip_runtime.h>
#include <hip/hip_bf16.h>
#include <hip/hip_fp16.h>
#include <cstddef>

// Problem constants: B=64, T=512, D=1024, H=1024
#define BATCH 64
#define TT    512
#define DD    1024
#define HH    1024

typedef _Float16 f16x8 __attribute__((ext_vector_type(8)));
typedef float    f32x4 __attribute__((ext_vector_type(4)));

// ---------------- Kernel A: xp = x @ Wx + bias, written into d_out ----------
#define BM 64
#define BN 64
#define BK 16
#define TM 4
#define TN 4

__global__ __launch_bounds__(256) void gemm_xp(
    const float* __restrict__ A,    // [M, K] = x
    const float* __restrict__ Bw,   // [K, N] = Wx
    const float* __restrict__ bias, // [N]
    float* __restrict__ C)          // [M, N] -> xp (into d_out)
{
    const int N = HH;
    const int K = DD;

    __shared__ float As[BK][BM + 1];
    __shared__ float Bs[BK][BN];

    const int tid  = threadIdx.x;
    const int brow = blockIdx.y * BM;
    const int bcol = blockIdx.x * BN;

    const int tcol = (tid % 16) * TN;
    const int trow = (tid / 16) * TM;

    float acc[TM][TN];
#pragma unroll
    for (int m = 0; m < TM; ++m)
#pragma unroll
        for (int n = 0; n < TN; ++n) acc[m][n] = 0.f;

    for (int k0 = 0; k0 < K; k0 += BK) {
#pragma unroll
        for (int i = tid; i < BM * BK; i += 256) {
            int r = i / BK, c = i % BK;
            As[c][r] = A[(size_t)(brow + r) * K + (k0 + c)];
        }
#pragma unroll
        for (int i = tid; i < BK * BN; i += 256) {
            int r = i / BN, c = i % BN;
            Bs[r][c] = Bw[(size_t)(k0 + r) * N + (bcol + c)];
        }
        __syncthreads();

#pragma unroll
        for (int k = 0; k < BK; ++k) {
            float a[TM], bv[TN];
#pragma unroll
            for (int m = 0; m < TM; ++m) a[m] = As[k][trow + m];
#pragma unroll
            for (int n = 0; n < TN; ++n) bv[n] = Bs[k][tcol + n];
#pragma unroll
            for (int m = 0; m < TM; ++m)
#pragma unroll
                for (int n = 0; n < TN; ++n) acc[m][n] += a[m] * bv[n];
        }
        __syncthreads();
    }

#pragma unroll
    for (int m = 0; m < TM; ++m) {
        size_t row = (size_t)(brow + trow + m) * N;
#pragma unroll
        for (int n = 0; n < TN; ++n) {
            int col = bcol + tcol + n;
            C[row + col] = acc[m][n] + bias[col];
        }
    }
}

// ---------------- Kernel B0: Wh f32 -> fp16, MFMA-B-fragment order ----------
// Whf[(((cg*32 + kk)*64) + lane)*8 + e] = Wh[k][col]
//   k = kk*32 + (lane>>4)*8 + e, col = cg*16 + (lane&15).
// Also zeroes the 256 per-wave barrier flags (deterministic per launch).
__global__ __launch_bounds__(256) void convert_whf(
    const float* __restrict__ Wh, _Float16* __restrict__ Whf,
    unsigned int* __restrict__ flags)
{
    if (blockIdx.x == 0) flags[threadIdx.x] = 0u;

    int tid = blockIdx.x * 256 + threadIdx.x;   // tid = k*1024 + col
    int k   = tid >> 10;
    int col = tid & 1023;
    float v = Wh[tid];
    int cg   = col >> 4;
    int kk   = k >> 5;
    int lane = ((k >> 3) & 3) * 16 + (col & 15);
    int e    = k & 7;
    Whf[((size_t)(cg * 32 + kk) * 64 + lane) * 8 + e] = (_Float16)v;
}

// ---------------- Kernel B: persistent scan, B-frags pinned in VGPRs -------
// 64 blocks x 256 threads (4 waves). bg = bid&3 (batch group of 16 rows),
// wave wid = (bid>>2)*4 + w owns col-group cg = wid (16 cols).
// Per-wave flag barrier over the 64 waves sharing bg: release-store
// flags[bg*64+wid] = t+1 after h_t stored; waiters lane-parallel acquire-poll
// all 64 flags. No __syncthreads, no atomic RMW. h double-buffered fp16.
__global__ __launch_bounds__(256, 1) void rnn_persist(
    const _Float16* __restrict__ Whf,   // frag-ordered [64][32][64][8]
    _Float16* __restrict__ hb0,         // [64][1024] fp16
    _Float16* __restrict__ hb1,         // [64][1024] fp16
    float* __restrict__ out,            // [64][512][1024]; xp -> h in place
    unsigned int* __restrict__ flags)   // [4][64] per-wave step counters
{
    const int bid  = blockIdx.x;
    const int bg   = bid & 3;
    const int w    = threadIdx.x >> 6;
    const int wid  = (bid >> 2) * 4 + w;   // 0..63 — also the col group
    const int cg   = wid;
    const int lane = threadIdx.x & 63;
    const int l15  = lane & 15;
    const int lq   = lane >> 4;
    const int col  = cg * 16 + l15;

    // ---- Load B fragments once; pin them in VGPRs (128 regs). ----
    f16x8 bfrag[32];
    {
        const f16x8* wp = (const f16x8*)Whf + ((size_t)cg * 32 * 64 + lane);
#pragma unroll
        for (int kk = 0; kk < 32; ++kk) bfrag[kk] = wp[(size_t)kk * 64];
    }
#pragma unroll
    for (int kk = 0; kk < 32; ++kk) asm volatile("" : "+v"(bfrag[kk]));

    unsigned int* gf = flags + bg * 64;
    _Float16* hbuf[2] = {hb0, hb1};

    // Per-lane xp/out addresses (row base, + t*HH per step).
    size_t o0[4];
#pragma unroll
    for (int v = 0; v < 4; ++v) {
        int b = bg * 16 + lq * 4 + v;      // C/D: row = 4*lq + v, col = l15
        o0[v] = (size_t)b * TT * HH + col;
    }

    // Preload xp for t = 0.
    float xpv[4];
#pragma unroll
    for (int v = 0; v < 4; ++v) xpv[v] = out[o0[v]];

    for (int t = 0; t < TT; ++t) {
        // Prefetch xp for t+1 BEFORE the wait — completes during the poll.
        float xpn[4] = {0.f, 0.f, 0.f, 0.f};
        if (t + 1 < TT) {
#pragma unroll
            for (int v = 0; v < 4; ++v) xpn[v] = out[o0[v] + (size_t)(t + 1) * HH];
        }

        f32x4 acc0 = {0,0,0,0}, acc1 = {0,0,0,0}, acc2 = {0,0,0,0}, acc3 = {0,0,0,0};

        if (t > 0) {
            // Wait: all 64 producer waves of this group finished step t-1.
            while (true) {
                unsigned int fv = __hip_atomic_load(gf + lane, __ATOMIC_ACQUIRE,
                                                    __HIP_MEMORY_SCOPE_AGENT);
                if (__all((int)(fv >= (unsigned int)t))) break;
            }
            const _Float16* ap = hbuf[(t + 1) & 1] + (size_t)(bg * 16 + l15) * HH + lq * 8;
            f16x8 a[32];
#pragma unroll
            for (int kk = 0; kk < 32; ++kk)
                a[kk] = *(const f16x8*)(ap + kk * 32);
#pragma unroll
            for (int q = 0; q < 8; ++q) {
                acc0 = __builtin_amdgcn_mfma_f32_16x16x32_f16(a[q*4+0], bfrag[q*4+0], acc0, 0, 0, 0);
                acc1 = __builtin_amdgcn_mfma_f32_16x16x32_f16(a[q*4+1], bfrag[q*4+1], acc1, 0, 0, 0);
                acc2 = __builtin_amdgcn_mfma_f32_16x16x32_f16(a[q*4+2], bfrag[q*4+2], acc2, 0, 0, 0);
                acc3 = __builtin_amdgcn_mfma_f32_16x16x32_f16(a[q*4+3], bfrag[q*4+3], acc3, 0, 0, 0);
            }
        }

        // Epilogue: h = tanh(acc + xp); store fp16 h first (critical path).
        _Float16* hn = hbuf[t & 1];
        float hv[4];
#pragma unroll
        for (int v = 0; v < 4; ++v) {
            float s = (acc0[v] + acc1[v]) + (acc2[v] + acc3[v]);
            hv[v] = tanhf(s + xpv[v]);
            int b = bg * 16 + lq * 4 + v;
            hn[(size_t)b * HH + col] = (_Float16)hv[v];
        }

        // Release h_t to the group.
        __threadfence();
        if (lane == 0)
            __hip_atomic_store(gf + wid, (unsigned int)(t + 1), __ATOMIC_RELAXED,
                               __HIP_MEMORY_SCOPE_AGENT);

        // Output stores — off the critical path.
#pragma unroll
        for (int v = 0; v < 4; ++v) out[o0[v] + (size_t)t * HH] = hv[v];

#pragma unroll
        for (int v = 0; v < 4; ++v) xpv[v] = xpn[v];
    }
}

extern "C" void kernel_launch(void* const* d_in, const int* in_sizes, int n_in,
                              void* d_out, int out_size, void* d_ws, size_t ws_size,
                              hipStream_t stream) {
    const float* x    = (const float*)d_in[0]; // [B, T, D]
    const float* Wx   = (const float*)d_in[1]; // [D, H]
    const float* Wh   = (const float*)d_in[2]; // [H, H]
    const float* bias = (const float*)d_in[3]; // [H]

    float* out = (float*)d_out;                // [B, T, H]

    // Workspace: Whf (2 MB) | hb0 (128 KB) | hb1 (128 KB) | flags (1 KB)
    _Float16* Whf = (_Float16*)d_ws;
    _Float16* hb0 = Whf + (1u << 20);
    _Float16* hb1 = hb0 + BATCH * HH;
    unsigned int* flags = (unsigned int*)(hb1 + BATCH * HH);

    // Wh -> fp16 frag order; zeroes the 256 barrier flags.
    convert_whf<<<4096, 256, 0, stream>>>(Wh, Whf, flags);

    // xp = x @ Wx + bias -> d_out
    dim3 gridA(HH / BN, (BATCH * TT) / BM);
    gemm_xp<<<gridA, 256, 0, stream>>>(x, Wx, bias, out);

    // Whole scan in one persistent kernel (64 blocks, co-resident).
    rnn_persist<<<64, 256, 0, stream>>>(Whf, hb0, hb1, out, flags);
}

// Round 5
// 6306.541 us; speedup vs baseline: 1.5486x; 1.5486x over previous
//
#include <hip/hip_runtime.h>
#include <hip/hip_bf16.h>
#include <hip/hip_fp16.h>
#include <cstddef>

// Problem constants: B=64, T=512, D=1024, H=1024
#define BATCH 64
#define TT    512
#define DD    1024
#define HH    1024

typedef _Float16 f16x8 __attribute__((ext_vector_type(8)));
typedef _Float16 f16x4 __attribute__((ext_vector_type(4)));
typedef float    f32x4 __attribute__((ext_vector_type(4)));
typedef unsigned long long u64;

union H8U2 { f16x8 v; u64 u[2]; };
union H4U1 { f16x4 h; u64 u; };

#define MFMA16(a, b, c) __builtin_amdgcn_mfma_f32_16x16x32_f16((a), (b), (c), 0, 0, 0)

// ---- convert: W [1024][1024] f32 row-major -> A-fragment-order f16 --------
// Wf[((cg*32+kk)*64+lane)*8+e] = W[k][c]  with  k = kk*32+(lane>>4)*8+e,
// c = cg*16+(lane&15).  (Same physical layout verified in rounds 1-4.)
// Optionally zeroes the 256 barrier flags.
__global__ __launch_bounds__(256) void convert_w(
    const float* __restrict__ W, _Float16* __restrict__ Wf,
    unsigned int* __restrict__ flags)
{
    if (flags && blockIdx.x == 0) flags[threadIdx.x] = 0u;

    int tid = blockIdx.x * 256 + threadIdx.x;   // tid = k*1024 + c
    int k   = tid >> 10;
    int c   = tid & 1023;
    float v = W[tid];
    int cg   = c >> 4;
    int kk   = k >> 5;
    int lane = ((k >> 3) & 3) * 16 + (c & 15);
    int e    = k & 7;
    Wf[((size_t)(cg * 32 + kk) * 64 + lane) * 8 + e] = (_Float16)v;
}

// ---- Kernel A: xp = x @ Wx + bias via f16 MFMA (transposed orientation) ---
// M = channel (1024), N = token (B*T = 32768), K = D.
// Wave holds ONE 16-token x-tile resident as B-frags (128 VGPR/AGPR),
// sweeps all 64 channel-tiles streaming WxA fragments (L2-resident, 2 MB).
__global__ __launch_bounds__(256, 1) void gemm_xp_mfma(
    const float* __restrict__ x,     // [32768][1024] f32
    const _Float16* __restrict__ WxA,// frag-ordered Wx^T
    const float* __restrict__ bias,  // [1024]
    float* __restrict__ out)         // [32768][1024] -> xp
{
    const int w    = threadIdx.x >> 6;
    const int lane = threadIdx.x & 63;
    const int l15  = lane & 15;
    const int lq   = lane >> 4;
    const int token0 = (blockIdx.x * 4 + w) * 16;   // 512 blocks * 4 waves = 2048 tiles

    // Resident B-frags: x[token0+l15][kk*32 + lq*8 .. +7], cvt f32->f16.
    f16x8 bfrag[32];
    {
        const float* xb = x + (size_t)(token0 + l15) * DD + lq * 8;
#pragma unroll
        for (int kk = 0; kk < 32; ++kk) {
            f32x4 lo = *(const f32x4*)(xb + kk * 32);
            f32x4 hi = *(const f32x4*)(xb + kk * 32 + 4);
            f16x8 f;
#pragma unroll
            for (int j = 0; j < 4; ++j) { f[j] = (_Float16)lo[j]; f[4 + j] = (_Float16)hi[j]; }
            bfrag[kk] = f;
        }
    }
#pragma unroll
    for (int kk = 0; kk < 32; ++kk) asm volatile("" : "+v"(bfrag[kk]));

    const size_t outb = (size_t)(token0 + l15) * HH + 4 * lq;

    for (int cg = 0; cg < 64; ++cg) {
        const f16x8* ap = (const f16x8*)WxA + (size_t)cg * 32 * 64 + lane;
        f16x8 a[32];
#pragma unroll
        for (int kk = 0; kk < 32; ++kk) a[kk] = ap[(size_t)kk * 64];

        f32x4 acc0 = {0,0,0,0}, acc1 = {0,0,0,0}, acc2 = {0,0,0,0}, acc3 = {0,0,0,0};
#pragma unroll
        for (int q = 0; q < 8; ++q) {
            acc0 = MFMA16(a[q*4+0], bfrag[q*4+0], acc0);
            acc1 = MFMA16(a[q*4+1], bfrag[q*4+1], acc1);
            acc2 = MFMA16(a[q*4+2], bfrag[q*4+2], acc2);
            acc3 = MFMA16(a[q*4+3], bfrag[q*4+3], acc3);
        }
        f32x4 bv = *(const f32x4*)(bias + cg * 16 + 4 * lq);
        f32x4 r;
#pragma unroll
        for (int v = 0; v < 4; ++v)
            r[v] = ((acc0[v] + acc1[v]) + (acc2[v] + acc3[v])) + bv[v];
        *(f32x4*)(out + outb + cg * 16) = r;   // 4 consecutive channels, one token
    }
}

// ---- Kernel B: persistent scan, h moved through L3 via relaxed atomics ----
// Transposed orientation: h_new^T[c][b] = sum_k Wh^T[c][k] * h^T[k][b].
// A = Wh^T frags resident (AGPR/VGPR). B = h rows, read as 2x8B relaxed
// agent atomics (coherence-point reads -> no cache invalidation anywhere).
// Producer: packed 8B atomic h-store -> vmcnt(0) -> relaxed flag store.
// Consumer: relaxed flag poll (no acquire), then atomic data loads.
__global__ __launch_bounds__(256, 1) void rnn_persist(
    const _Float16* __restrict__ Whf,   // frag-ordered Wh^T
    _Float16* __restrict__ hb0,         // [64][1024] f16
    _Float16* __restrict__ hb1,         // [64][1024] f16
    float* __restrict__ out,            // [64][512][1024]; xp -> h in place
    unsigned int* __restrict__ flags)   // [4][64] per-wave step counters
{
    const int bid  = blockIdx.x;
    const int bg   = bid & 3;               // batch group (16 rows)
    const int w    = threadIdx.x >> 6;
    const int cg   = (bid >> 2) * 4 + w;    // 0..63 channel group
    const int lane = threadIdx.x & 63;
    const int l15  = lane & 15;
    const int lq   = lane >> 4;

    // Resident A-frags (Wh^T): 32 x f16x8.
    f16x8 afrag[32];
    {
        const f16x8* wp = (const f16x8*)Whf + (size_t)cg * 32 * 64 + lane;
#pragma unroll
        for (int kk = 0; kk < 32; ++kk) afrag[kk] = wp[(size_t)kk * 64];
    }
#pragma unroll
    for (int kk = 0; kk < 32; ++kk) asm volatile("" : "+v"(afrag[kk]));

    unsigned int* gf = flags + bg * 64;

    const int b = bg * 16 + l15;            // this lane's batch row (read AND write)
    const int c = cg * 16 + 4 * lq;         // first of this lane's 4 channels

    // h read pointers: h[b][kk*32 + lq*8] as u64 pairs.
    const u64* hr[2] = {
        (const u64*)(hb0 + (size_t)b * HH) + lq * 2,
        (const u64*)(hb1 + (size_t)b * HH) + lq * 2,
    };
    // h write pointers: h[b][c..c+3] packed as one u64.
    u64* hw[2] = {
        (u64*)(hb0 + (size_t)b * HH + c),
        (u64*)(hb1 + (size_t)b * HH + c),
    };

    const size_t ob = (size_t)b * TT * HH + c;

    f32x4 xpv = *(const f32x4*)(out + ob);  // xp for t=0

    for (int t = 0; t < TT; ++t) {
        f32x4 acc0 = {0,0,0,0}, acc1 = {0,0,0,0}, acc2 = {0,0,0,0}, acc3 = {0,0,0,0};

        if (t > 0) {
            // Relaxed poll: all 64 producer waves of this group stored h_{t-1}.
            while (true) {
                unsigned int fv = __hip_atomic_load(gf + lane, __ATOMIC_RELAXED,
                                                    __HIP_MEMORY_SCOPE_AGENT);
                if (__all((int)(fv >= (unsigned int)t))) break;
            }
            const u64* hp = hr[(t + 1) & 1];
            f16x8 bfr[32];
#pragma unroll
            for (int kk = 0; kk < 32; ++kk) {
                H8U2 uu;
                uu.u[0] = __hip_atomic_load(hp + kk * 8,     __ATOMIC_RELAXED,
                                            __HIP_MEMORY_SCOPE_AGENT);
                uu.u[1] = __hip_atomic_load(hp + kk * 8 + 1, __ATOMIC_RELAXED,
                                            __HIP_MEMORY_SCOPE_AGENT);
                bfr[kk] = uu.v;
            }
#pragma unroll
            for (int q = 0; q < 8; ++q) {
                acc0 = MFMA16(afrag[q*4+0], bfr[q*4+0], acc0);
                acc1 = MFMA16(afrag[q*4+1], bfr[q*4+1], acc1);
                acc2 = MFMA16(afrag[q*4+2], bfr[q*4+2], acc2);
                acc3 = MFMA16(afrag[q*4+3], bfr[q*4+3], acc3);
            }
        }

        // h = tanh(acc + xp): 4 consecutive channels of batch b.
        f32x4 hvv;
        H4U1 pk;
#pragma unroll
        for (int v = 0; v < 4; ++v) {
            float s = ((acc0[v] + acc1[v]) + (acc2[v] + acc3[v])) + xpv[v];
            hvv[v] = tanhf(s);
            pk.h[v] = (_Float16)hvv[v];
        }

        // Packed 8B h-store to the coherence point, then order, then flag.
        __hip_atomic_store(hw[t & 1], pk.u, __ATOMIC_RELAXED, __HIP_MEMORY_SCOPE_AGENT);
        asm volatile("s_waitcnt vmcnt(0)" ::: "memory");
        if (lane == 0)
            __hip_atomic_store(gf + cg, (unsigned int)(t + 1), __ATOMIC_RELAXED,
                               __HIP_MEMORY_SCOPE_AGENT);

        // Off critical path: fp32 out store + next xp prefetch (drained by
        // next iteration's vmcnt(0), overlaps the next poll).
        *(f32x4*)(out + ob + (size_t)t * HH) = hvv;
        if (t + 1 < TT) xpv = *(const f32x4*)(out + ob + (size_t)(t + 1) * HH);
    }
}

extern "C" void kernel_launch(void* const* d_in, const int* in_sizes, int n_in,
                              void* d_out, int out_size, void* d_ws, size_t ws_size,
                              hipStream_t stream) {
    const float* x    = (const float*)d_in[0]; // [B, T, D]
    const float* Wx   = (const float*)d_in[1]; // [D, H]
    const float* Wh   = (const float*)d_in[2]; // [H, H]
    const float* bias = (const float*)d_in[3]; // [H]

    float* out = (float*)d_out;                // [B, T, H]

    // Workspace: Whf (2MB) | WxA (2MB) | hb0 (128KB) | hb1 (128KB) | flags (1KB)
    _Float16* Whf = (_Float16*)d_ws;
    _Float16* WxA = Whf + (1u << 20);
    _Float16* hb0 = WxA + (1u << 20);
    _Float16* hb1 = hb0 + BATCH * HH;
    unsigned int* flags = (unsigned int*)(hb1 + BATCH * HH);

    // Weight conversions (Wh call also zeroes the 256 flags).
    convert_w<<<4096, 256, 0, stream>>>(Wh, Whf, flags);
    convert_w<<<4096, 256, 0, stream>>>(Wx, WxA, nullptr);

    // xp = x @ Wx + bias (f16 MFMA, transposed orientation)
    gemm_xp_mfma<<<512, 256, 0, stream>>>(x, WxA, bias, out);

    // Whole scan in one persistent kernel (64 blocks, co-resident).
    rnn_persist<<<64, 256, 0, stream>>>(Whf, hb0, hb1, out, flags);
}

// Round 6
// 4472.227 us; speedup vs baseline: 2.1838x; 1.4102x over previous
//
#include <hip/hip_runtime.h>
#include <hip/hip_bf16.h>
#include <hip/hip_fp16.h>
#include <cstddef>

// Problem constants: B=64, T=512, D=1024, H=1024
#define BATCH 64
#define TT    512
#define DD    1024
#define HH    1024

typedef _Float16 f16x8 __attribute__((ext_vector_type(8)));
typedef _Float16 f16x4 __attribute__((ext_vector_type(4)));
typedef float    f32x4 __attribute__((ext_vector_type(4)));
typedef unsigned long long u64;

union H8U2 { f16x8 v; u64 u[2]; };
union H4U1 { f16x4 h; u64 u; };

#define MFMA16(a, b, c) __builtin_amdgcn_mfma_f32_16x16x32_f16((a), (b), (c), 0, 0, 0)

// ---- convert: W [1024][1024] f32 row-major -> A-fragment-order f16 --------
// Wf[((cg*32+kk)*64+lane)*8+e] = W[k][c]  with  k = kk*32+(lane>>4)*8+e,
// c = cg*16+(lane&15).  (Layout verified rounds 1-5.)
// Optionally zeroes the h double-buffer (tag reset, 256 KB via first 128 blks).
__global__ __launch_bounds__(256) void convert_w(
    const float* __restrict__ W, _Float16* __restrict__ Wf,
    u64* __restrict__ hzero)
{
    if (hzero && blockIdx.x < 128)
        hzero[(size_t)blockIdx.x * 256 + threadIdx.x] = 0ull;

    int tid = blockIdx.x * 256 + threadIdx.x;   // tid = k*1024 + c
    int k   = tid >> 10;
    int c   = tid & 1023;
    float v = W[tid];
    int cg   = c >> 4;
    int kk   = k >> 5;
    int lane = ((k >> 3) & 3) * 16 + (c & 15);
    int e    = k & 7;
    Wf[((size_t)(cg * 32 + kk) * 64 + lane) * 8 + e] = (_Float16)v;
}

// ---- Kernel A: xp = x @ Wx + bias via f16 MFMA (transposed orientation) ---
// (unchanged from round 5 — worked, absmax fine)
__global__ __launch_bounds__(256, 1) void gemm_xp_mfma(
    const float* __restrict__ x,     // [32768][1024] f32
    const _Float16* __restrict__ WxA,// frag-ordered Wx^T
    const float* __restrict__ bias,  // [1024]
    float* __restrict__ out)         // [32768][1024] -> xp
{
    const int w    = threadIdx.x >> 6;
    const int lane = threadIdx.x & 63;
    const int l15  = lane & 15;
    const int lq   = lane >> 4;
    const int token0 = (blockIdx.x * 4 + w) * 16;

    f16x8 bfrag[32];
    {
        const float* xb = x + (size_t)(token0 + l15) * DD + lq * 8;
#pragma unroll
        for (int kk = 0; kk < 32; ++kk) {
            f32x4 lo = *(const f32x4*)(xb + kk * 32);
            f32x4 hi = *(const f32x4*)(xb + kk * 32 + 4);
            f16x8 f;
#pragma unroll
            for (int j = 0; j < 4; ++j) { f[j] = (_Float16)lo[j]; f[4 + j] = (_Float16)hi[j]; }
            bfrag[kk] = f;
        }
    }
#pragma unroll
    for (int kk = 0; kk < 32; ++kk) asm volatile("" : "+v"(bfrag[kk]));

    const size_t outb = (size_t)(token0 + l15) * HH + 4 * lq;

    for (int cg = 0; cg < 64; ++cg) {
        const f16x8* ap = (const f16x8*)WxA + (size_t)cg * 32 * 64 + lane;
        f16x8 a[32];
#pragma unroll
        for (int kk = 0; kk < 32; ++kk) a[kk] = ap[(size_t)kk * 64];

        f32x4 acc0 = {0,0,0,0}, acc1 = {0,0,0,0}, acc2 = {0,0,0,0}, acc3 = {0,0,0,0};
#pragma unroll
        for (int q = 0; q < 8; ++q) {
            acc0 = MFMA16(a[q*4+0], bfrag[q*4+0], acc0);
            acc1 = MFMA16(a[q*4+1], bfrag[q*4+1], acc1);
            acc2 = MFMA16(a[q*4+2], bfrag[q*4+2], acc2);
            acc3 = MFMA16(a[q*4+3], bfrag[q*4+3], acc3);
        }
        f32x4 bv = *(const f32x4*)(bias + cg * 16 + 4 * lq);
        f32x4 r;
#pragma unroll
        for (int v = 0; v < 4; ++v)
            r[v] = ((acc0[v] + acc1[v]) + (acc2[v] + acc3[v])) + bv[v];
        *(f32x4*)(out + outb + cg * 16) = r;
    }
}

// ---- Kernel B: persistent scan, flag-free tagged-data handoff via L3 ------
// h_new^T[c][b] = sum_k Wh^T[c][k] * h^T[k][b]. A = Wh^T frags resident.
// Producer lane stores its 4 f16 h-values as ONE 8B sc0|sc1 store, with a
// 2-bit step tag (1 + t mod 3) hidden in the LSB of f16 elem 0 (dword 0)
// and elem 2 (dword 1) — each dword is written atomically, each carries its
// own tag bit. Consumers poll the DATA: 32 pipelined 16B sc0|sc1 loads,
// check 4 tag bits per unit, retry until all fresh. No flags, no fences,
// no acquire/release — L3 is the coherence point for every h byte.
// Double buffer is race-free: a producer can be at most 1 step ahead
// (it needs this reader's published h to advance), and mod-3 tags differ
// at buffer-reuse distance 2. Tag 0 (poison/zeroed) is never valid.
__global__ __launch_bounds__(256, 1) void rnn_persist(
    const _Float16* __restrict__ Whf,   // frag-ordered Wh^T
    _Float16* __restrict__ hb0,         // [64][1024] f16 (tagged)
    _Float16* __restrict__ hb1,         // [64][1024] f16 (tagged)
    float* __restrict__ out)            // [64][512][1024]; xp -> h in place
{
    const int bid  = blockIdx.x;
    const int bg   = bid & 3;               // batch group (16 rows)
    const int w    = threadIdx.x >> 6;
    const int cg   = (bid >> 2) * 4 + w;    // 0..63 channel group
    const int lane = threadIdx.x & 63;
    const int l15  = lane & 15;
    const int lq   = lane >> 4;

    // Resident A-frags (Wh^T): 32 x f16x8, pinned.
    f16x8 afrag[32];
    {
        const f16x8* wp = (const f16x8*)Whf + (size_t)cg * 32 * 64 + lane;
#pragma unroll
        for (int kk = 0; kk < 32; ++kk) afrag[kk] = wp[(size_t)kk * 64];
    }
#pragma unroll
    for (int kk = 0; kk < 32; ++kk) asm volatile("" : "+v"(afrag[kk]));

    const int b = bg * 16 + l15;            // this lane's batch row
    const int c = cg * 16 + 4 * lq;         // first of this lane's 4 channels

    // Consumer read bases: h[b][kk*32 + lq*8 ..], 16B units.
    const _Float16* hr[2] = {
        hb0 + (size_t)b * HH + lq * 8,
        hb1 + (size_t)b * HH + lq * 8,
    };
    // Producer write base: h[b][c..c+3] as one u64.
    _Float16* hw[2] = {
        hb0 + (size_t)b * HH + c,
        hb1 + (size_t)b * HH + c,
    };

    const size_t ob = (size_t)b * TT * HH + c;

    f32x4 xpv = *(const f32x4*)(out + ob);  // xp for t=0

    unsigned tagw = 1u;                     // tag for step t   (1 + t%3)
    unsigned tagr = 0u;                     // tag for step t-1

    for (int t = 0; t < TT; ++t) {
        f32x4 acc0 = {0,0,0,0}, acc1 = {0,0,0,0}, acc2 = {0,0,0,0}, acc3 = {0,0,0,0};

        if (t > 0) {
            const _Float16* hp = hr[(t + 1) & 1];
            f16x8 bfr[32];
            while (true) {
                H8U2 uu[32];
#pragma unroll
                for (int kk = 0; kk < 32; ++kk) {
                    const _Float16* p = hp + kk * 32;
                    asm volatile("global_load_dwordx4 %0, %1, off sc0 sc1"
                                 : "=v"(uu[kk].v) : "v"(p));
                }
                __builtin_amdgcn_sched_barrier(0);
                asm volatile("s_waitcnt vmcnt(0)" ::: "memory");
                __builtin_amdgcn_sched_barrier(0);

                unsigned good = 1u;
#pragma unroll
                for (int kk = 0; kk < 32; ++kk) {
                    u64 lo = uu[kk].u[0], hi = uu[kk].u[1];
                    unsigned ta = (unsigned)(lo & 1u) | (((unsigned)(lo >> 32) & 1u) << 1);
                    unsigned tb = (unsigned)(hi & 1u) | (((unsigned)(hi >> 32) & 1u) << 1);
                    good &= (unsigned)(ta == tagr) & (unsigned)(tb == tagr);
                    bfr[kk] = uu[kk].v;
                }
                if (__all((int)good)) break;
                __builtin_amdgcn_s_sleep(1);
            }
#pragma unroll
            for (int q = 0; q < 8; ++q) {
                acc0 = MFMA16(afrag[q*4+0], bfr[q*4+0], acc0);
                acc1 = MFMA16(afrag[q*4+1], bfr[q*4+1], acc1);
                acc2 = MFMA16(afrag[q*4+2], bfr[q*4+2], acc2);
                acc3 = MFMA16(afrag[q*4+3], bfr[q*4+3], acc3);
            }
        }

        // h = tanh(acc + xp): 4 consecutive channels of batch b.
        f32x4 hvv;
        H4U1 pk;
#pragma unroll
        for (int v = 0; v < 4; ++v) {
            float s = ((acc0[v] + acc1[v]) + (acc2[v] + acc3[v])) + xpv[v];
            hvv[v] = tanhf(s);
            pk.h[v] = (_Float16)hvv[v];
        }
        // Embed 2-bit tag: LSB of elem0 (dword0) = tagw&1, elem2 (dword1) = tagw>>1.
        pk.u = (pk.u & ~(1ull | (1ull << 32)))
             | (u64)(tagw & 1u) | ((u64)(tagw >> 1) << 32);

        // One 8B write-through store — the entire inter-wave handoff.
        {
            _Float16* q = hw[t & 1];
            asm volatile("global_store_dwordx2 %0, %1, off sc0 sc1"
                         :: "v"(q), "v"(pk.u) : "memory");
        }

        // Off critical path: fp32 out store + next xp prefetch.
        *(f32x4*)(out + ob + (size_t)t * HH) = hvv;
        if (t + 1 < TT) xpv = *(const f32x4*)(out + ob + (size_t)(t + 1) * HH);

        tagr = tagw;
        tagw = (tagw == 3u) ? 1u : tagw + 1u;
    }
}

extern "C" void kernel_launch(void* const* d_in, const int* in_sizes, int n_in,
                              void* d_out, int out_size, void* d_ws, size_t ws_size,
                              hipStream_t stream) {
    const float* x    = (const float*)d_in[0]; // [B, T, D]
    const float* Wx   = (const float*)d_in[1]; // [D, H]
    const float* Wh   = (const float*)d_in[2]; // [H, H]
    const float* bias = (const float*)d_in[3]; // [H]

    float* out = (float*)d_out;                // [B, T, H]

    // Workspace: Whf (2MB) | WxA (2MB) | hb0 (128KB) | hb1 (128KB)
    _Float16* Whf = (_Float16*)d_ws;
    _Float16* WxA = Whf + (1u << 20);
    _Float16* hb0 = WxA + (1u << 20);
    _Float16* hb1 = hb0 + BATCH * HH;

    // Weight conversions; the Wh pass also zeroes hb0/hb1 (tag reset, so a
    // graph replay can never see a stale-but-valid tag from the previous run).
    convert_w<<<4096, 256, 0, stream>>>(Wh, Whf, (u64*)hb0);
    convert_w<<<4096, 256, 0, stream>>>(Wx, WxA, nullptr);

    // xp = x @ Wx + bias (f16 MFMA)
    gemm_xp_mfma<<<512, 256, 0, stream>>>(x, WxA, bias, out);

    // Whole scan in one persistent kernel (64 blocks, co-resident).
    rnn_persist<<<64, 256, 0, stream>>>(Whf, hb0, hb1, out);
}